// Round 5
// baseline (210.541 us; speedup 1.0000x reference)
//
#include <hip/hip_runtime.h>
#include <hip/hip_bf16.h>

#define B_  4
#define S_  2048
#define D_  768
#define H_  12
#define DH_ 64

typedef __bf16 bf16;
typedef __attribute__((ext_vector_type(8))) __bf16 bf16x8;
typedef __attribute__((ext_vector_type(4))) __bf16 bf16x4;
typedef __attribute__((ext_vector_type(4))) float floatx4;

// 128-row q-tiles (qt2 0..15); kt-tiles of 64 keys, chunks of <=8 kt-tiles.
// nkt(qt2)=2qt2+2, nch=ceil(nkt/8); chunk_off2 = flat offset of (qt2,c=0) in
// the 40 chunks per bh.
__device__ __forceinline__ int chunk_off2(int qt2) {
    if (qt2 < 4)  return qt2;
    if (qt2 < 8)  return 4 + 2 * (qt2 - 4);
    if (qt2 < 12) return 12 + 3 * (qt2 - 8);
    return 24 + 4 * (qt2 - 12);
}

__device__ __forceinline__ unsigned pack_bf16(float a, float b) {
    unsigned short ua = __builtin_bit_cast(unsigned short, (bf16)a);
    unsigned short ub = __builtin_bit_cast(unsigned short, (bf16)b);
    return (unsigned)ua | ((unsigned)ub << 16);
}

// ---------------- fp32 -> bf16 conversion (vectorized) ----------------
__global__ __launch_bounds__(256) void cvt_f32_bf16(const float* __restrict__ in,
                                                    bf16* __restrict__ out, int n4) {
    int i = blockIdx.x * 256 + threadIdx.x;
    if (i < n4) {
        float4 v = ((const float4*)in)[i];
        bf16x4 o;
        o[0] = (bf16)v.x; o[1] = (bf16)v.y; o[2] = (bf16)v.z; o[3] = (bf16)v.w;
        *(bf16x4*)(out + (size_t)i * 4) = o;
    }
}

// ---------------- W transpose: W[k][n] f32 -> Wt[n][k] bf16 ----------------
__global__ __launch_bounds__(256) void w_transpose(const float* __restrict__ w0,
                                                   const float* __restrict__ w1,
                                                   const float* __restrict__ w2,
                                                   bf16* __restrict__ Wt)
{
    const int which = blockIdx.z;
    const float* W = (which == 0) ? w0 : (which == 1 ? w1 : w2);
    bf16* dst = Wt + (size_t)which * D_ * D_;
    __shared__ bf16 t[64 * 72];
    const int k0 = blockIdx.x * 64, n0 = blockIdx.y * 64;
    const int tid = threadIdx.x;
    {
        int r = tid >> 2;
        int c0 = (tid & 3) * 16;
        #pragma unroll
        for (int q = 0; q < 4; q++) {
            float4 v = *(const float4*)(W + (size_t)(k0 + r) * D_ + n0 + c0 + q * 4);
            t[(c0 + q * 4 + 0) * 72 + r] = (bf16)v.x;
            t[(c0 + q * 4 + 1) * 72 + r] = (bf16)v.y;
            t[(c0 + q * 4 + 2) * 72 + r] = (bf16)v.z;
            t[(c0 + q * 4 + 3) * 72 + r] = (bf16)v.w;
        }
    }
    __syncthreads();
    {
        int n = tid >> 3, seg = tid & 7;
        *(bf16x8*)(dst + (size_t)(n0 + n) * D_ + k0 + seg * 8) =
            *(const bf16x8*)(t + n * 72 + seg * 8);
        *(bf16x8*)(dst + (size_t)(n0 + n + 32) * D_ + k0 + seg * 8) =
            *(const bf16x8*)(t + (n + 32) * 72 + seg * 8);
    }
}

// ---------------- QKV projection GEMM ----------------
// 128x128 tile, BK=64, register-prefetch. Q output pre-scaled by 1/8 (exact
// exponent shift in bf16) so attention skips the scale.
// Q,K scattered to [B,H,S,DH]; V written TRANSPOSED to [B,H,DH,S].
__global__ __launch_bounds__(256) void qkv_gemm(
    const bf16* __restrict__ Xb, const bf16* __restrict__ Wt,
    const float* __restrict__ bq, const float* __restrict__ bk,
    const float* __restrict__ bv, bf16* __restrict__ QKV)
{
    const int which = blockIdx.z;
    const bf16* Wm = Wt + (size_t)which * D_ * D_;
    const float* bias = (which == 0) ? bq : (which == 1 ? bk : bv);
    bf16* out = QKV + (size_t)which * B_ * H_ * S_ * DH_;

    __shared__ bf16 As[128 * 72];
    __shared__ bf16 Bs[128 * 72];

    const int tid  = threadIdx.x;
    const int wave = tid >> 6, lane = tid & 63;
    const int wr = wave >> 1, wc = wave & 1;
    const int g = lane >> 4, ln = lane & 15;
    const int m0 = blockIdx.x * 128, n0 = blockIdx.y * 128;

    floatx4 acc[4][4];
    #pragma unroll
    for (int i = 0; i < 4; i++)
        #pragma unroll
        for (int j = 0; j < 4; j++)
            acc[i][j] = (floatx4){0.f, 0.f, 0.f, 0.f};

    int row_[4], seg_[4];
    #pragma unroll
    for (int t = 0; t < 4; t++) { int fc = tid + t * 256; row_[t] = fc >> 3; seg_[t] = fc & 7; }

    bf16x8 apf[4], bpf[4];
    #pragma unroll
    for (int t = 0; t < 4; t++) {
        apf[t] = *(const bf16x8*)(Xb + (size_t)(m0 + row_[t]) * D_ + seg_[t] * 8);
        bpf[t] = *(const bf16x8*)(Wm + (size_t)(n0 + row_[t]) * D_ + seg_[t] * 8);
    }

    for (int k0 = 0; k0 < D_; k0 += 64) {
        __syncthreads();
        #pragma unroll
        for (int t = 0; t < 4; t++) {
            *(bf16x8*)(As + row_[t] * 72 + seg_[t] * 8) = apf[t];
            *(bf16x8*)(Bs + row_[t] * 72 + seg_[t] * 8) = bpf[t];
        }
        __syncthreads();
        if (k0 + 64 < D_) {
            #pragma unroll
            for (int t = 0; t < 4; t++) {
                apf[t] = *(const bf16x8*)(Xb + (size_t)(m0 + row_[t]) * D_ + k0 + 64 + seg_[t] * 8);
                bpf[t] = *(const bf16x8*)(Wm + (size_t)(n0 + row_[t]) * D_ + k0 + 64 + seg_[t] * 8);
            }
        }
        #pragma unroll
        for (int ks = 0; ks < 2; ks++) {
            bf16x8 af[4], bfr[4];
            #pragma unroll
            for (int i = 0; i < 4; i++)
                af[i] = *(const bf16x8*)(As + (wr * 64 + i * 16 + ln) * 72 + ks * 32 + g * 8);
            #pragma unroll
            for (int j = 0; j < 4; j++)
                bfr[j] = *(const bf16x8*)(Bs + (wc * 64 + j * 16 + ln) * 72 + ks * 32 + g * 8);
            #pragma unroll
            for (int i = 0; i < 4; i++)
                #pragma unroll
                for (int j = 0; j < 4; j++)
                    acc[i][j] = __builtin_amdgcn_mfma_f32_16x16x32_bf16(af[i], bfr[j], acc[i][j], 0, 0, 0);
        }
    }

    const float sc = (which == 0) ? 0.125f : 1.0f;   // fold 1/sqrt(DH) into Q
    #pragma unroll
    for (int i = 0; i < 4; i++) {
        #pragma unroll
        for (int j = 0; j < 4; j++) {
            int col = n0 + wc * 64 + j * 16 + ln;
            float bv_ = bias[col];
            int h = col >> 6, dh = col & 63;
            int rowbase = m0 + wr * 64 + i * 16 + g * 4;
            int b = rowbase >> 11, s0 = rowbase & 2047;
            if (which == 2) {
                bf16x4 o;
                #pragma unroll
                for (int r = 0; r < 4; r++) o[r] = (bf16)(acc[i][j][r] + bv_);
                *(bf16x4*)(out + ((size_t)((b * H_ + h) * DH_ + dh)) * S_ + s0) = o;
            } else {
                #pragma unroll
                for (int r = 0; r < 4; r++)
                    out[(((size_t)(b * H_ + h) * S_ + s0 + r) << 6) + dh] =
                        (bf16)((acc[i][j][r] + bv_) * sc);
            }
        }
    }
}

// ---------------- Flash attention, transposed (O^T = V^T P^T) ----------------
// 128 q-rows per block, fixed-max softmax (additive partials). S^T = K Q^T:
// C-layout cols are q. P^T enters PV as the B-operand, assembled from S^T's
// C-layout registers by cross-lane __shfl (no LDS roundtrip, no Ps buffer).
__global__ __launch_bounds__(256) void attn_chunk(const bf16* __restrict__ QKV,
                                                  float* __restrict__ out,
                                                  bf16* __restrict__ Opart,
                                                  float* __restrict__ Lpart)
{
    const int cid = 39 - blockIdx.x;   // heavy q-tiles dispatch first
    const int bh = blockIdx.y;
    const int b = bh / H_, h = bh % H_;

    int qt2, c;
    if (cid < 4)       { qt2 = cid; c = 0; }
    else if (cid < 12) { int t = cid - 4;  qt2 = 4 + (t >> 1);  c = t & 1; }
    else if (cid < 24) { int t = cid - 12; qt2 = 8 + t / 3;     c = t - 3 * (t / 3); }
    else               { int t = cid - 24; qt2 = 12 + (t >> 2); c = t & 3; }
    const int nch = (2 * qt2 + 9) >> 3;
    const int kt0 = c * 8;
    const int kt1 = min(kt0 + 7, 2 * qt2 + 1);

    const size_t MAT = (size_t)B_ * H_ * S_ * DH_;
    const bf16* Q  = QKV +           (size_t)bh * S_ * DH_;  // [s][dh], pre-scaled 1/8
    const bf16* K  = QKV + MAT +     (size_t)bh * S_ * DH_;  // [s][dh]
    const bf16* Vt = QKV + 2 * MAT + (size_t)bh * S_ * DH_;  // [dh][s]

    __shared__ bf16 Ks[64 * 72];    // [key][dh]
    __shared__ bf16 Vts[64 * 72];   // [dh][key]

    const int tid  = threadIdx.x;
    const int wave = tid >> 6, lane = tid & 63;
    const int g = lane >> 4, ln = lane & 15;
    const int srow = tid >> 3, sseg = tid & 7;
    const int qbase = qt2 * 128;

    // Q fragments as B-operand: lane holds Q[q = qbase+t*64+wave*16+ln][k]
    bf16x8 qf[2][2];
    #pragma unroll
    for (int t = 0; t < 2; t++) {
        const bf16* qrow = Q + (size_t)(qbase + t * 64 + wave * 16 + ln) * DH_;
        qf[t][0] = *(const bf16x8*)(qrow + g * 8);
        qf[t][1] = *(const bf16x8*)(qrow + 32 + g * 8);
    }

    bf16x8 ones;
    #pragma unroll
    for (int i = 0; i < 8; i++) ones[i] = (bf16)1.0f;

    floatx4 accO[2][4];   // O^T tiles: [q-set][dh-tile]
    #pragma unroll
    for (int t = 0; t < 2; t++)
        #pragma unroll
        for (int j = 0; j < 4; j++) accO[t][j] = (floatx4){0.f, 0.f, 0.f, 0.f};
    floatx4 accL[2] = {(floatx4){0.f, 0.f, 0.f, 0.f}, (floatx4){0.f, 0.f, 0.f, 0.f}};

    const bf16* kptr = K  + (size_t)(kt0 * 64 + srow) * DH_ + sseg * 8;
    const bf16* vptr = Vt + (size_t)srow * S_ + kt0 * 64 + sseg * 8;
    bf16x8 ka = *(const bf16x8*)kptr;
    bf16x8 kb = *(const bf16x8*)(kptr + 32 * DH_);
    bf16x8 va = *(const bf16x8*)vptr;
    bf16x8 vb = *(const bf16x8*)(vptr + (size_t)32 * S_);

    // shuffle source lanes for the C->B-frag transpose
    const int s0lane = ((lane >> 4) & 1) * 32 + ln;   // group (g&1)*2
    const bool hi = (lane >= 32);                     // target g>=2 -> odd tile

    for (int kt = kt0; kt <= kt1; ++kt) {
        __syncthreads();
        *(bf16x8*)(Ks  + srow * 72 + sseg * 8) = ka;
        *(bf16x8*)(Ks  + (srow + 32) * 72 + sseg * 8) = kb;
        *(bf16x8*)(Vts + srow * 72 + sseg * 8) = va;
        *(bf16x8*)(Vts + (srow + 32) * 72 + sseg * 8) = vb;
        __syncthreads();
        if (kt < kt1) {
            kptr += 64 * DH_;
            vptr += 64;
            ka = *(const bf16x8*)kptr;
            kb = *(const bf16x8*)(kptr + 32 * DH_);
            va = *(const bf16x8*)vptr;
            vb = *(const bf16x8*)(vptr + (size_t)32 * S_);
        }

        // K fragments as A-operand: lane holds K[key = kt*64+j*16+ln][k]
        bf16x8 kf[4][2];
        #pragma unroll
        for (int j = 0; j < 4; j++)
            #pragma unroll
            for (int cc = 0; cc < 2; cc++)
                kf[j][cc] = *(const bf16x8*)(Ks + (j * 16 + ln) * 72 + cc * 32 + g * 8);

        // S^T = K Q^T : D[m=key][n=q]; C layout: reg r -> key=j*16+g*4+r, q=ln
        floatx4 accS[2][4];
        #pragma unroll
        for (int t = 0; t < 2; t++)
            #pragma unroll
            for (int j = 0; j < 4; j++) accS[t][j] = (floatx4){0.f, 0.f, 0.f, 0.f};
        #pragma unroll
        for (int t = 0; t < 2; t++)
            #pragma unroll
            for (int j = 0; j < 4; j++)
                #pragma unroll
                for (int cc = 0; cc < 2; cc++)
                    accS[t][j] = __builtin_amdgcn_mfma_f32_16x16x32_bf16(
                        kf[j][cc], qf[t][cc], accS[t][j], 0, 0, 0);

        // p = exp(s) (scale pre-folded into Q); causal mask; pack to bf16 pairs
        unsigned pd0[2][4], pd1[2][4];
        #pragma unroll
        for (int t = 0; t < 2; t++) {
            const int qg = qbase + t * 64 + wave * 16 + ln;
            const bool domask = (kt >= 2 * qt2 + t);
            #pragma unroll
            for (int j = 0; j < 4; j++) {
                float p[4];
                #pragma unroll
                for (int r = 0; r < 4; r++) {
                    p[r] = __expf(accS[t][j][r]);
                    if (domask) {
                        int key = kt * 64 + j * 16 + g * 4 + r;
                        if (key > qg) p[r] = 0.f;
                    }
                }
                pd0[t][j] = pack_bf16(p[0], p[1]);
                pd1[t][j] = pack_bf16(p[2], p[3]);
            }
        }

        // PV: O^T += V^T P^T ; P^T B-frag gathered by cross-lane shuffles
        #pragma unroll
        for (int cc = 0; cc < 2; cc++) {
            bf16x8 ptf[2];
            #pragma unroll
            for (int t = 0; t < 2; t++) {
                unsigned a0 = __shfl(pd0[t][2 * cc],     s0lane);
                unsigned b0 = __shfl(pd0[t][2 * cc + 1], s0lane);
                unsigned a1 = __shfl(pd1[t][2 * cc],     s0lane);
                unsigned b1 = __shfl(pd1[t][2 * cc + 1], s0lane);
                unsigned a2 = __shfl(pd0[t][2 * cc],     s0lane + 16);
                unsigned b2 = __shfl(pd0[t][2 * cc + 1], s0lane + 16);
                unsigned a3 = __shfl(pd1[t][2 * cc],     s0lane + 16);
                unsigned b3 = __shfl(pd1[t][2 * cc + 1], s0lane + 16);
                uint4 w;
                w.x = hi ? b0 : a0;
                w.y = hi ? b1 : a1;
                w.z = hi ? b2 : a2;
                w.w = hi ? b3 : a3;
                ptf[t] = __builtin_bit_cast(bf16x8, w);
                accL[t] = __builtin_amdgcn_mfma_f32_16x16x32_bf16(ones, ptf[t], accL[t], 0, 0, 0);
            }
            #pragma unroll
            for (int j = 0; j < 4; j++) {
                bf16x8 vf = *(const bf16x8*)(Vts + (j * 16 + ln) * 72 + cc * 32 + g * 8);
                #pragma unroll
                for (int t = 0; t < 2; t++)
                    accO[t][j] = __builtin_amdgcn_mfma_f32_16x16x32_bf16(
                        vf, ptf[t], accO[t][j], 0, 0, 0);
            }
        }
    }

    if (nch == 1) {
        // O^T C-layout: q = ln, dh = j*16 + g*4 + r -> float4 stores
        #pragma unroll
        for (int t = 0; t < 2; t++) {
            float inv = 1.0f / accL[t][0];
            int q = qbase + t * 64 + wave * 16 + ln;
            float* orow = out + (size_t)(b * S_ + q) * D_ + h * DH_;
            #pragma unroll
            for (int j = 0; j < 4; j++) {
                float4 o;
                o.x = accO[t][j][0] * inv; o.y = accO[t][j][1] * inv;
                o.z = accO[t][j][2] * inv; o.w = accO[t][j][3] * inv;
                *(float4*)(orow + j * 16 + g * 4) = o;
            }
        }
    } else {
        const int chunk = bh * 40 + chunk_off2(qt2) + c;
        bf16* obase = Opart + (size_t)chunk * 8192;
        #pragma unroll
        for (int t = 0; t < 2; t++) {
            int ql = t * 64 + wave * 16 + ln;
            #pragma unroll
            for (int j = 0; j < 4; j++) {
                bf16x4 o;
                #pragma unroll
                for (int r = 0; r < 4; r++) o[r] = (bf16)accO[t][j][r];
                *(bf16x4*)(obase + ql * 64 + j * 16 + g * 4) = o;
            }
            if (g == 0) Lpart[chunk * 128 + ql] = accL[t][0];
        }
    }
}

// ---------------- reduce: sum chunk partials, normalize, write out ----------
__global__ __launch_bounds__(256) void attn_reduce(const bf16* __restrict__ Opart,
                                                   const float* __restrict__ Lpart,
                                                   float* __restrict__ out)
{
    const int qt2 = 4 + blockIdx.x;   // 4..15
    const int bh = blockIdx.y;
    const int b = bh / H_, h = bh % H_;
    const int nch = (2 * qt2 + 9) >> 3;   // 2..4
    const int cb = bh * 40 + chunk_off2(qt2);

    const int e = threadIdx.x;
    const int ql = e >> 1, dh0 = (e & 1) * 32;

    float o[32];
    #pragma unroll
    for (int i = 0; i < 32; i++) o[i] = 0.f;
    float l = 0.f;

    for (int cidx = 0; cidx < nch; cidx++) {
        const bf16* p = Opart + (size_t)(cb + cidx) * 8192 + ql * 64 + dh0;
        #pragma unroll
        for (int m = 0; m < 4; m++) {
            bf16x8 v = *(const bf16x8*)(p + m * 8);
            #pragma unroll
            for (int k = 0; k < 8; k++) o[m * 8 + k] += (float)v[k];
        }
        l += Lpart[(cb + cidx) * 128 + ql];
    }
    float inv = 1.0f / l;
    float* orow = out + (size_t)(b * S_ + qt2 * 128 + ql) * D_ + h * DH_ + dh0;
    #pragma unroll
    for (int m = 0; m < 8; m++) {
        float4 v;
        v.x = o[m * 4 + 0] * inv; v.y = o[m * 4 + 1] * inv;
        v.z = o[m * 4 + 2] * inv; v.w = o[m * 4 + 3] * inv;
        *(float4*)(orow + m * 4) = v;
    }
}

extern "C" void kernel_launch(void* const* d_in, const int* in_sizes, int n_in,
                              void* d_out, int out_size, void* d_ws, size_t ws_size,
                              hipStream_t stream) {
    const float* hs = (const float*)d_in[0];
    // d_in[1] attention_mask: zeros, unused (matches reference)
    const float* Wq = (const float*)d_in[2];
    const float* bq = (const float*)d_in[3];
    const float* Wk = (const float*)d_in[4];
    const float* bk = (const float*)d_in[5];
    const float* Wv = (const float*)d_in[6];
    const float* bv = (const float*)d_in[7];
    float* out = (float*)d_out;

    bf16* Xb    = (bf16*)d_ws;                            // 8192*768
    bf16* Wt    = Xb + (size_t)8192 * 768;                // 3*768*768 (transposed)
    bf16* QKV   = Wt + (size_t)3 * 768 * 768;             // Q,K:[B,H,S,DH]; V:[B,H,DH,S]
    bf16* Opart = QKV + (size_t)3 * B_ * H_ * S_ * DH_;   // 1920*8192 bf16
    float* Lpart = (float*)(Opart + (size_t)1920 * 8192); // 1920*128 f32

    cvt_f32_bf16<<<6144, 256, 0, stream>>>(hs, Xb, 1572864);
    w_transpose<<<dim3(12, 12, 3), 256, 0, stream>>>(Wq, Wk, Wv, Wt);
    qkv_gemm<<<dim3(64, 6, 3), 256, 0, stream>>>(Xb, Wt, bq, bk, bv, QKV);
    attn_chunk<<<dim3(40, 48), 256, 0, stream>>>(QKV, out, Opart, Lpart);
    attn_reduce<<<dim3(12, 48), 256, 0, stream>>>(Opart, Lpart, out);
}

// Round 6
// 206.969 us; speedup vs baseline: 1.0173x; 1.0173x over previous
//
#include <hip/hip_runtime.h>
#include <hip/hip_bf16.h>

#define B_  4
#define S_  2048
#define D_  768
#define H_  12
#define DH_ 64

typedef __bf16 bf16;
typedef __attribute__((ext_vector_type(8))) __bf16 bf16x8;
typedef __attribute__((ext_vector_type(4))) __bf16 bf16x4;
typedef __attribute__((ext_vector_type(4))) float floatx4;
typedef __attribute__((ext_vector_type(16))) float floatx16;

// 128-row q-tiles (qt2 0..15); kt-tiles of 64 keys, chunks of <=8 kt-tiles.
// nkt(qt2)=2qt2+2, nch=ceil(nkt/8); chunk_off2 = flat offset of (qt2,c=0) in
// the 40 chunks per bh.
__device__ __forceinline__ int chunk_off2(int qt2) {
    if (qt2 < 4)  return qt2;
    if (qt2 < 8)  return 4 + 2 * (qt2 - 4);
    if (qt2 < 12) return 12 + 3 * (qt2 - 8);
    return 24 + 4 * (qt2 - 12);
}

__device__ __forceinline__ unsigned pack_bf16(float a, float b) {
    unsigned short ua = __builtin_bit_cast(unsigned short, (bf16)a);
    unsigned short ub = __builtin_bit_cast(unsigned short, (bf16)b);
    return (unsigned)ua | ((unsigned)ub << 16);
}

// ---------------- fp32 -> bf16 conversion (vectorized) ----------------
__global__ __launch_bounds__(256) void cvt_f32_bf16(const float* __restrict__ in,
                                                    bf16* __restrict__ out, int n4) {
    int i = blockIdx.x * 256 + threadIdx.x;
    if (i < n4) {
        float4 v = ((const float4*)in)[i];
        bf16x4 o;
        o[0] = (bf16)v.x; o[1] = (bf16)v.y; o[2] = (bf16)v.z; o[3] = (bf16)v.w;
        *(bf16x4*)(out + (size_t)i * 4) = o;
    }
}

// ---------------- W transpose: W[k][n] f32 -> Wt[n][k] bf16 ----------------
__global__ __launch_bounds__(256) void w_transpose(const float* __restrict__ w0,
                                                   const float* __restrict__ w1,
                                                   const float* __restrict__ w2,
                                                   bf16* __restrict__ Wt)
{
    const int which = blockIdx.z;
    const float* W = (which == 0) ? w0 : (which == 1 ? w1 : w2);
    bf16* dst = Wt + (size_t)which * D_ * D_;
    __shared__ bf16 t[64 * 72];
    const int k0 = blockIdx.x * 64, n0 = blockIdx.y * 64;
    const int tid = threadIdx.x;
    {
        int r = tid >> 2;
        int c0 = (tid & 3) * 16;
        #pragma unroll
        for (int q = 0; q < 4; q++) {
            float4 v = *(const float4*)(W + (size_t)(k0 + r) * D_ + n0 + c0 + q * 4);
            t[(c0 + q * 4 + 0) * 72 + r] = (bf16)v.x;
            t[(c0 + q * 4 + 1) * 72 + r] = (bf16)v.y;
            t[(c0 + q * 4 + 2) * 72 + r] = (bf16)v.z;
            t[(c0 + q * 4 + 3) * 72 + r] = (bf16)v.w;
        }
    }
    __syncthreads();
    {
        int n = tid >> 3, seg = tid & 7;
        *(bf16x8*)(dst + (size_t)(n0 + n) * D_ + k0 + seg * 8) =
            *(const bf16x8*)(t + n * 72 + seg * 8);
        *(bf16x8*)(dst + (size_t)(n0 + n + 32) * D_ + k0 + seg * 8) =
            *(const bf16x8*)(t + (n + 32) * 72 + seg * 8);
    }
}

// ---------------- QKV projection GEMM ----------------
// 128x128 tile, BK=64, register-prefetch. Q output pre-scaled by 1/8 so the
// attention kernel skips the scale. Q,K -> [B,H,S,DH]; V -> [B,H,DH,S].
__global__ __launch_bounds__(256) void qkv_gemm(
    const bf16* __restrict__ Xb, const bf16* __restrict__ Wt,
    const float* __restrict__ bq, const float* __restrict__ bk,
    const float* __restrict__ bv, bf16* __restrict__ QKV)
{
    const int which = blockIdx.z;
    const bf16* Wm = Wt + (size_t)which * D_ * D_;
    const float* bias = (which == 0) ? bq : (which == 1 ? bk : bv);
    bf16* out = QKV + (size_t)which * B_ * H_ * S_ * DH_;

    __shared__ bf16 As[128 * 72];
    __shared__ bf16 Bs[128 * 72];

    const int tid  = threadIdx.x;
    const int wave = tid >> 6, lane = tid & 63;
    const int wr = wave >> 1, wc = wave & 1;
    const int g = lane >> 4, ln = lane & 15;
    const int m0 = blockIdx.x * 128, n0 = blockIdx.y * 128;

    floatx4 acc[4][4];
    #pragma unroll
    for (int i = 0; i < 4; i++)
        #pragma unroll
        for (int j = 0; j < 4; j++)
            acc[i][j] = (floatx4){0.f, 0.f, 0.f, 0.f};

    int row_[4], seg_[4];
    #pragma unroll
    for (int t = 0; t < 4; t++) { int fc = tid + t * 256; row_[t] = fc >> 3; seg_[t] = fc & 7; }

    bf16x8 apf[4], bpf[4];
    #pragma unroll
    for (int t = 0; t < 4; t++) {
        apf[t] = *(const bf16x8*)(Xb + (size_t)(m0 + row_[t]) * D_ + seg_[t] * 8);
        bpf[t] = *(const bf16x8*)(Wm + (size_t)(n0 + row_[t]) * D_ + seg_[t] * 8);
    }

    for (int k0 = 0; k0 < D_; k0 += 64) {
        __syncthreads();
        #pragma unroll
        for (int t = 0; t < 4; t++) {
            *(bf16x8*)(As + row_[t] * 72 + seg_[t] * 8) = apf[t];
            *(bf16x8*)(Bs + row_[t] * 72 + seg_[t] * 8) = bpf[t];
        }
        __syncthreads();
        if (k0 + 64 < D_) {
            #pragma unroll
            for (int t = 0; t < 4; t++) {
                apf[t] = *(const bf16x8*)(Xb + (size_t)(m0 + row_[t]) * D_ + k0 + 64 + seg_[t] * 8);
                bpf[t] = *(const bf16x8*)(Wm + (size_t)(n0 + row_[t]) * D_ + k0 + 64 + seg_[t] * 8);
            }
        }
        #pragma unroll
        for (int ks = 0; ks < 2; ks++) {
            bf16x8 af[4], bfr[4];
            #pragma unroll
            for (int i = 0; i < 4; i++)
                af[i] = *(const bf16x8*)(As + (wr * 64 + i * 16 + ln) * 72 + ks * 32 + g * 8);
            #pragma unroll
            for (int j = 0; j < 4; j++)
                bfr[j] = *(const bf16x8*)(Bs + (wc * 64 + j * 16 + ln) * 72 + ks * 32 + g * 8);
            #pragma unroll
            for (int i = 0; i < 4; i++)
                #pragma unroll
                for (int j = 0; j < 4; j++)
                    acc[i][j] = __builtin_amdgcn_mfma_f32_16x16x32_bf16(af[i], bfr[j], acc[i][j], 0, 0, 0);
        }
    }

    const float sc = (which == 0) ? 0.125f : 1.0f;   // fold 1/sqrt(DH) into Q
    #pragma unroll
    for (int i = 0; i < 4; i++) {
        #pragma unroll
        for (int j = 0; j < 4; j++) {
            int col = n0 + wc * 64 + j * 16 + ln;
            float bv_ = bias[col];
            int h = col >> 6, dh = col & 63;
            int rowbase = m0 + wr * 64 + i * 16 + g * 4;
            int b = rowbase >> 11, s0 = rowbase & 2047;
            if (which == 2) {
                bf16x4 o;
                #pragma unroll
                for (int r = 0; r < 4; r++) o[r] = (bf16)(acc[i][j][r] + bv_);
                *(bf16x4*)(out + ((size_t)((b * H_ + h) * DH_ + dh)) * S_ + s0) = o;
            } else {
                #pragma unroll
                for (int r = 0; r < 4; r++)
                    out[(((size_t)(b * H_ + h) * S_ + s0 + r) << 6) + dh] =
                        (bf16)((acc[i][j][r] + bv_) * sc);
            }
        }
    }
}

// ---------------- Flash attention, 32x32x16 MFMA, transposed ----------------
// O^T = V^T P^T per 32-q wave slice. S^T = K Q^T with Q B-frags hoisted out
// of the kt loop. C->B-frag transform for P^T: 2 shfl_xor(32) + selects per
// kstep (8 shuffles/wave-iter). L = per-lane register sum + ONE shuffle at end.
__global__ __launch_bounds__(256) void attn_chunk(const bf16* __restrict__ QKV,
                                                  float* __restrict__ out,
                                                  bf16* __restrict__ Opart,
                                                  float* __restrict__ Lpart)
{
    const int cid = 39 - blockIdx.x;   // heavy q-tiles dispatch first
    const int bh = blockIdx.y;
    const int b = bh / H_, h = bh % H_;

    int qt2, c;
    if (cid < 4)       { qt2 = cid; c = 0; }
    else if (cid < 12) { int t = cid - 4;  qt2 = 4 + (t >> 1);  c = t & 1; }
    else if (cid < 24) { int t = cid - 12; qt2 = 8 + t / 3;     c = t - 3 * (t / 3); }
    else               { int t = cid - 24; qt2 = 12 + (t >> 2); c = t & 3; }
    const int nch = (2 * qt2 + 9) >> 3;
    const int kt0 = c * 8;
    const int kt1 = min(kt0 + 7, 2 * qt2 + 1);

    const size_t MAT = (size_t)B_ * H_ * S_ * DH_;
    const bf16* Q  = QKV +           (size_t)bh * S_ * DH_;  // [s][dh], pre-scaled 1/8
    const bf16* K  = QKV + MAT +     (size_t)bh * S_ * DH_;  // [s][dh]
    const bf16* Vt = QKV + 2 * MAT + (size_t)bh * S_ * DH_;  // [dh][s]

    __shared__ bf16 Ks[64 * 72];    // [key][dh]
    __shared__ bf16 Vts[64 * 72];   // [dh][key]

    const int tid  = threadIdx.x;
    const int wave = tid >> 6, lane = tid & 63;
    const int l31 = lane & 31, lh = lane >> 5;
    const int srow = tid >> 3, sseg = tid & 7;
    const int qbase = qt2 * 128;
    const int qs = qbase + wave * 32;     // wave's 32-q slice
    const int q = qs + l31;               // this lane's q column

    // Q B-frags for all 4 ksteps, held in registers across the whole kt loop.
    // B[k=dh][col=q]: lane holds Q[q][16s + lh*8 + i]
    bf16x8 qf[4];
    {
        const bf16* qrow = Q + (size_t)q * DH_ + lh * 8;
        #pragma unroll
        for (int s = 0; s < 4; s++) qf[s] = *(const bf16x8*)(qrow + s * 16);
    }

    floatx16 accO[2];   // O^T: dh-tile dt -> rows dt*32+rho, col q
    #pragma unroll
    for (int dt = 0; dt < 2; dt++)
        #pragma unroll
        for (int e = 0; e < 16; e++) accO[dt][e] = 0.f;
    float Lrun = 0.f;   // per-lane partial row sum (own lane-half keys only)

    const bf16* kptr = K  + (size_t)(kt0 * 64 + srow) * DH_ + sseg * 8;
    const bf16* vptr = Vt + (size_t)srow * S_ + kt0 * 64 + sseg * 8;
    bf16x8 ka = *(const bf16x8*)kptr;
    bf16x8 kb = *(const bf16x8*)(kptr + 32 * DH_);
    bf16x8 va = *(const bf16x8*)vptr;
    bf16x8 vb = *(const bf16x8*)(vptr + (size_t)32 * S_);

    for (int kt = kt0; kt <= kt1; ++kt) {
        __syncthreads();
        *(bf16x8*)(Ks  + srow * 72 + sseg * 8) = ka;
        *(bf16x8*)(Ks  + (srow + 32) * 72 + sseg * 8) = kb;
        *(bf16x8*)(Vts + srow * 72 + sseg * 8) = va;
        *(bf16x8*)(Vts + (srow + 32) * 72 + sseg * 8) = vb;
        __syncthreads();
        if (kt < kt1) {
            kptr += 64 * DH_;
            vptr += 64;
            ka = *(const bf16x8*)kptr;
            kb = *(const bf16x8*)(kptr + 32 * DH_);
            va = *(const bf16x8*)vptr;
            vb = *(const bf16x8*)(vptr + (size_t)32 * S_);
        }

        // S^T = K Q^T: two 32-key tiles kk, k=dh in 4 ksteps of 16.
        // A-frag: Ks[kk*32 + l31][16s + lh*8 .. +7]
        floatx16 accS[2];
        #pragma unroll
        for (int kk = 0; kk < 2; kk++) {
            #pragma unroll
            for (int e = 0; e < 16; e++) accS[kk][e] = 0.f;
            #pragma unroll
            for (int s = 0; s < 4; s++) {
                bf16x8 kf = *(const bf16x8*)(Ks + (kk * 32 + l31) * 72 + s * 16 + lh * 8);
                accS[kk] = __builtin_amdgcn_mfma_f32_32x32x16_bf16(kf, qf[s], accS[kk], 0, 0, 0);
            }
        }

        // p = exp(s); causal mask; pack to bf16 pairs.
        // C layout: col q = l31, row rho = rr + 8*rq + 4*lh (reg = 4rq+rr).
        unsigned pk1[2][4], pk2[2][4];
        const bool domask = (kt * 64 + 63 > qs);
        #pragma unroll
        for (int kk = 0; kk < 2; kk++) {
            const int keyb = kt * 64 + kk * 32 + 4 * lh;
            #pragma unroll
            for (int rq = 0; rq < 4; rq++) {
                float p[4];
                #pragma unroll
                for (int rr = 0; rr < 4; rr++) {
                    float v = __expf(accS[kk][4 * rq + rr]);
                    if (domask && (keyb + 8 * rq + rr > q)) v = 0.f;
                    p[rr] = v;
                    Lrun += v;
                }
                pk1[kk][rq] = pack_bf16(p[0], p[1]);
                pk2[kk][rq] = pack_bf16(p[2], p[3]);
            }
        }

        // PV: O^T += V^T P^T. B-frag for kstep s: C regs 4*(2(s&1)+lh')..+3
        // from both lane halves -> 2 shfl_xor(32) + selects per s.
        #pragma unroll
        for (int s = 0; s < 4; s++) {
            const int kk = s >> 1, sl = s & 1;
            unsigned sendA = lh ? pk1[kk][2 * sl] : pk1[kk][2 * sl + 1];
            unsigned sendB = lh ? pk2[kk][2 * sl] : pk2[kk][2 * sl + 1];
            unsigned recvA = __shfl_xor(sendA, 32, 64);
            unsigned recvB = __shfl_xor(sendB, 32, 64);
            uint4 w;
            w.x = lh ? recvA : pk1[kk][2 * sl];
            w.y = lh ? recvB : pk2[kk][2 * sl];
            w.z = lh ? pk1[kk][2 * sl + 1] : recvA;
            w.w = lh ? pk2[kk][2 * sl + 1] : recvB;
            bf16x8 ptf = __builtin_bit_cast(bf16x8, w);
            #pragma unroll
            for (int dt = 0; dt < 2; dt++) {
                bf16x8 vf = *(const bf16x8*)(Vts + (dt * 32 + l31) * 72 + s * 16 + lh * 8);
                accO[dt] = __builtin_amdgcn_mfma_f32_32x32x16_bf16(vf, ptf, accO[dt], 0, 0, 0);
            }
        }
    }

    // complete the row sum: own half + partner half (single shuffle)
    const float L = Lrun + __shfl_xor(Lrun, 32, 64);

    if (nch == 1) {
        const float inv = 1.0f / L;
        float* orow = out + (size_t)(b * S_ + q) * D_ + h * DH_;
        #pragma unroll
        for (int dt = 0; dt < 2; dt++)
            #pragma unroll
            for (int rq = 0; rq < 4; rq++) {
                float4 o;
                o.x = accO[dt][4 * rq + 0] * inv; o.y = accO[dt][4 * rq + 1] * inv;
                o.z = accO[dt][4 * rq + 2] * inv; o.w = accO[dt][4 * rq + 3] * inv;
                *(float4*)(orow + dt * 32 + 8 * rq + 4 * lh) = o;
            }
    } else {
        const int chunk = bh * 40 + chunk_off2(qt2) + c;
        bf16* obase = Opart + (size_t)chunk * 8192 + (wave * 32 + l31) * 64;
        #pragma unroll
        for (int dt = 0; dt < 2; dt++)
            #pragma unroll
            for (int rq = 0; rq < 4; rq++) {
                bf16x4 o;
                #pragma unroll
                for (int rr = 0; rr < 4; rr++) o[rr] = (bf16)accO[dt][4 * rq + rr];
                *(bf16x4*)(obase + dt * 32 + 8 * rq + 4 * lh) = o;
            }
        if (lh == 0) Lpart[chunk * 128 + wave * 32 + l31] = L;
    }
}

// ---------------- reduce: sum chunk partials, normalize, write out ----------
__global__ __launch_bounds__(256) void attn_reduce(const bf16* __restrict__ Opart,
                                                   const float* __restrict__ Lpart,
                                                   float* __restrict__ out)
{
    const int qt2 = 4 + blockIdx.x;   // 4..15
    const int bh = blockIdx.y;
    const int b = bh / H_, h = bh % H_;
    const int nch = (2 * qt2 + 9) >> 3;   // 2..4
    const int cb = bh * 40 + chunk_off2(qt2);

    const int e = threadIdx.x;
    const int ql = e >> 1, dh0 = (e & 1) * 32;

    float o[32];
    #pragma unroll
    for (int i = 0; i < 32; i++) o[i] = 0.f;
    float l = 0.f;

    for (int cidx = 0; cidx < nch; cidx++) {
        const bf16* p = Opart + (size_t)(cb + cidx) * 8192 + ql * 64 + dh0;
        #pragma unroll
        for (int m = 0; m < 4; m++) {
            bf16x8 v = *(const bf16x8*)(p + m * 8);
            #pragma unroll
            for (int k = 0; k < 8; k++) o[m * 8 + k] += (float)v[k];
        }
        l += Lpart[(cb + cidx) * 128 + ql];
    }
    float inv = 1.0f / l;
    float* orow = out + (size_t)(b * S_ + qt2 * 128 + ql) * D_ + h * DH_ + dh0;
    #pragma unroll
    for (int m = 0; m < 8; m++) {
        float4 v;
        v.x = o[m * 4 + 0] * inv; v.y = o[m * 4 + 1] * inv;
        v.z = o[m * 4 + 2] * inv; v.w = o[m * 4 + 3] * inv;
        *(float4*)(orow + m * 4) = v;
    }
}

extern "C" void kernel_launch(void* const* d_in, const int* in_sizes, int n_in,
                              void* d_out, int out_size, void* d_ws, size_t ws_size,
                              hipStream_t stream) {
    const float* hs = (const float*)d_in[0];
    // d_in[1] attention_mask: zeros, unused (matches reference)
    const float* Wq = (const float*)d_in[2];
    const float* bq = (const float*)d_in[3];
    const float* Wk = (const float*)d_in[4];
    const float* bk = (const float*)d_in[5];
    const float* Wv = (const float*)d_in[6];
    const float* bv = (const float*)d_in[7];
    float* out = (float*)d_out;

    bf16* Xb    = (bf16*)d_ws;                            // 8192*768
    bf16* Wt    = Xb + (size_t)8192 * 768;                // 3*768*768 (transposed)
    bf16* QKV   = Wt + (size_t)3 * 768 * 768;             // Q,K:[B,H,S,DH]; V:[B,H,DH,S]
    bf16* Opart = QKV + (size_t)3 * B_ * H_ * S_ * DH_;   // 1920*8192 bf16
    float* Lpart = (float*)(Opart + (size_t)1920 * 8192); // 1920*128 f32

    cvt_f32_bf16<<<6144, 256, 0, stream>>>(hs, Xb, 1572864);
    w_transpose<<<dim3(12, 12, 3), 256, 0, stream>>>(Wq, Wk, Wv, Wt);
    qkv_gemm<<<dim3(64, 6, 3), 256, 0, stream>>>(Xb, Wt, bq, bk, bv, QKV);
    attn_chunk<<<dim3(40, 48), 256, 0, stream>>>(QKV, out, Opart, Lpart);
    attn_reduce<<<dim3(12, 48), 256, 0, stream>>>(Opart, Lpart, out);
}

// Round 7
// 202.936 us; speedup vs baseline: 1.0375x; 1.0199x over previous
//
#include <hip/hip_runtime.h>
#include <hip/hip_bf16.h>

#define B_  4
#define S_  2048
#define D_  768
#define H_  12
#define DH_ 64

typedef __bf16 bf16;
typedef __attribute__((ext_vector_type(8))) __bf16 bf16x8;
typedef __attribute__((ext_vector_type(4))) __bf16 bf16x4;
typedef __attribute__((ext_vector_type(4))) float floatx4;
typedef __attribute__((ext_vector_type(16))) float floatx16;

__device__ __forceinline__ void load_lds16(const bf16* g, bf16* l) {
    __builtin_amdgcn_global_load_lds((const __attribute__((address_space(1))) void*)g,
                                     (__attribute__((address_space(3))) void*)l, 16, 0, 0);
}

// pack two f32 -> packed bf16 pair (round-half-up: bias + v_perm, 3 ops)
__device__ __forceinline__ unsigned pack2(float a, float b) {
    unsigned ua = __builtin_bit_cast(unsigned, a) + 0x8000u;
    unsigned ub = __builtin_bit_cast(unsigned, b) + 0x8000u;
    return __builtin_amdgcn_perm(ub, ua, 0x07060302);
}

// 128-row q-tiles (qt2 0..15); kt-tiles of 64 keys, chunks of <=8 kt-tiles.
__device__ __forceinline__ int chunk_off2(int qt2) {
    if (qt2 < 4)  return qt2;
    if (qt2 < 8)  return 4 + 2 * (qt2 - 4);
    if (qt2 < 12) return 12 + 3 * (qt2 - 8);
    return 24 + 4 * (qt2 - 12);
}

// ---------------- fp32 -> bf16 conversion (vectorized) ----------------
__global__ __launch_bounds__(256) void cvt_f32_bf16(const float* __restrict__ in,
                                                    bf16* __restrict__ out, int n4) {
    int i = blockIdx.x * 256 + threadIdx.x;
    if (i < n4) {
        float4 v = ((const float4*)in)[i];
        bf16x4 o;
        o[0] = (bf16)v.x; o[1] = (bf16)v.y; o[2] = (bf16)v.z; o[3] = (bf16)v.w;
        *(bf16x4*)(out + (size_t)i * 4) = o;
    }
}

// ---------------- W transpose: W[k][n] f32 -> Wt[n][k] bf16 ----------------
__global__ __launch_bounds__(256) void w_transpose(const float* __restrict__ w0,
                                                   const float* __restrict__ w1,
                                                   const float* __restrict__ w2,
                                                   bf16* __restrict__ Wt)
{
    const int which = blockIdx.z;
    const float* W = (which == 0) ? w0 : (which == 1 ? w1 : w2);
    bf16* dst = Wt + (size_t)which * D_ * D_;
    __shared__ bf16 t[64 * 72];
    const int k0 = blockIdx.x * 64, n0 = blockIdx.y * 64;
    const int tid = threadIdx.x;
    {
        int r = tid >> 2;
        int c0 = (tid & 3) * 16;
        #pragma unroll
        for (int q = 0; q < 4; q++) {
            float4 v = *(const float4*)(W + (size_t)(k0 + r) * D_ + n0 + c0 + q * 4);
            t[(c0 + q * 4 + 0) * 72 + r] = (bf16)v.x;
            t[(c0 + q * 4 + 1) * 72 + r] = (bf16)v.y;
            t[(c0 + q * 4 + 2) * 72 + r] = (bf16)v.z;
            t[(c0 + q * 4 + 3) * 72 + r] = (bf16)v.w;
        }
    }
    __syncthreads();
    {
        int n = tid >> 3, seg = tid & 7;
        *(bf16x8*)(dst + (size_t)(n0 + n) * D_ + k0 + seg * 8) =
            *(const bf16x8*)(t + n * 72 + seg * 8);
        *(bf16x8*)(dst + (size_t)(n0 + n + 32) * D_ + k0 + seg * 8) =
            *(const bf16x8*)(t + (n + 32) * 72 + seg * 8);
    }
}

// ---------------- QKV projection GEMM (m97 structure) ----------------
// 128x128 tile, BK=64. global_load_lds width-16 direct DMA into unpadded
// XOR-swizzled LDS (swizzle applied on the GLOBAL address side: pure lane
// permutation, coalescing preserved; frag reads land 2-way = conflict-free).
__global__ __launch_bounds__(256) void qkv_gemm(
    const bf16* __restrict__ Xb, const bf16* __restrict__ Wt,
    const float* __restrict__ bq, const float* __restrict__ bk,
    const float* __restrict__ bv, bf16* __restrict__ QKV)
{
    const int which = blockIdx.z;
    const bf16* Wm = Wt + (size_t)which * D_ * D_;
    const float* bias = (which == 0) ? bq : (which == 1 ? bk : bv);
    bf16* out = QKV + (size_t)which * B_ * H_ * S_ * DH_;

    __shared__ bf16 As[128 * 64];   // unpadded, swizzled
    __shared__ bf16 Bs[128 * 64];

    const int tid  = threadIdx.x;
    const int wave = tid >> 6, lane = tid & 63;
    const int wr = wave >> 1, wc = wave & 1;
    const int g = lane >> 4, ln = lane & 15;
    const int m0 = blockIdx.x * 128, n0 = blockIdx.y * 128;
    const int fbase = wave * 256 + lane;   // lane-linear chunk index

    floatx4 acc[4][4];
    #pragma unroll
    for (int i = 0; i < 4; i++)
        #pragma unroll
        for (int j = 0; j < 4; j++)
            acc[i][j] = (floatx4){0.f, 0.f, 0.f, 0.f};

    for (int k0 = 0; k0 < D_; k0 += 64) {
        __syncthreads();
        #pragma unroll
        for (int i = 0; i < 4; i++) {
            int fc = fbase + i * 64;
            int row = fc >> 3;
            int seg = (fc & 7) ^ (row & 7);   // XOR swizzle on global side
            load_lds16(Xb + (size_t)(m0 + row) * D_ + k0 + seg * 8, As + fc * 8);
            load_lds16(Wm + (size_t)(n0 + row) * D_ + k0 + seg * 8, Bs + fc * 8);
        }
        __syncthreads();   // compiler drains vmcnt(0) before barrier
        #pragma unroll
        for (int ks = 0; ks < 2; ks++) {
            const int sx = ((ks * 4 + g) ^ (ln & 7)) * 8;   // swizzled k-offset
            bf16x8 af[4], bfr[4];
            #pragma unroll
            for (int i = 0; i < 4; i++)
                af[i] = *(const bf16x8*)(As + ((wr * 64 + i * 16 + ln) << 6) + sx);
            #pragma unroll
            for (int j = 0; j < 4; j++)
                bfr[j] = *(const bf16x8*)(Bs + ((wc * 64 + j * 16 + ln) << 6) + sx);
            #pragma unroll
            for (int i = 0; i < 4; i++)
                #pragma unroll
                for (int j = 0; j < 4; j++)
                    acc[i][j] = __builtin_amdgcn_mfma_f32_16x16x32_bf16(af[i], bfr[j], acc[i][j], 0, 0, 0);
        }
    }

    const float sc = (which == 0) ? 0.125f : 1.0f;   // fold 1/sqrt(DH) into Q
    #pragma unroll
    for (int i = 0; i < 4; i++) {
        #pragma unroll
        for (int j = 0; j < 4; j++) {
            int col = n0 + wc * 64 + j * 16 + ln;
            float bv_ = bias[col];
            int h = col >> 6, dh = col & 63;
            int rowbase = m0 + wr * 64 + i * 16 + g * 4;
            int b = rowbase >> 11, s0 = rowbase & 2047;
            if (which == 2) {
                bf16x4 o;
                #pragma unroll
                for (int r = 0; r < 4; r++) o[r] = (bf16)(acc[i][j][r] + bv_);
                *(bf16x4*)(out + ((size_t)((b * H_ + h) * DH_ + dh)) * S_ + s0) = o;
            } else {
                #pragma unroll
                for (int r = 0; r < 4; r++)
                    out[(((size_t)(b * H_ + h) * S_ + s0 + r) << 6) + dh] =
                        (bf16)((acc[i][j][r] + bv_) * sc);
            }
        }
    }
}

// ---------------- Flash attention, 32x32x16 MFMA, transposed ----------------
// Sequential kk-tile processing (lower live registers), wave-uniform mask
// branch, v_perm fast bf16 pack, 4-way split L partial sums.
__global__ __launch_bounds__(256, 3) void attn_chunk(const bf16* __restrict__ QKV,
                                                     float* __restrict__ out,
                                                     bf16* __restrict__ Opart,
                                                     float* __restrict__ Lpart)
{
    const int cid = 39 - blockIdx.x;   // heavy q-tiles dispatch first
    const int bh = blockIdx.y;
    const int b = bh / H_, h = bh % H_;

    int qt2, c;
    if (cid < 4)       { qt2 = cid; c = 0; }
    else if (cid < 12) { int t = cid - 4;  qt2 = 4 + (t >> 1);  c = t & 1; }
    else if (cid < 24) { int t = cid - 12; qt2 = 8 + t / 3;     c = t - 3 * (t / 3); }
    else               { int t = cid - 24; qt2 = 12 + (t >> 2); c = t & 3; }
    const int nch = (2 * qt2 + 9) >> 3;
    const int kt0 = c * 8;
    const int kt1 = min(kt0 + 7, 2 * qt2 + 1);

    const size_t MAT = (size_t)B_ * H_ * S_ * DH_;
    const bf16* Q  = QKV +           (size_t)bh * S_ * DH_;  // [s][dh], pre-scaled 1/8
    const bf16* K  = QKV + MAT +     (size_t)bh * S_ * DH_;  // [s][dh]
    const bf16* Vt = QKV + 2 * MAT + (size_t)bh * S_ * DH_;  // [dh][s]

    __shared__ bf16 Ks[64 * 72];    // [key][dh]
    __shared__ bf16 Vts[64 * 72];   // [dh][key]

    const int tid  = threadIdx.x;
    const int wave = tid >> 6, lane = tid & 63;
    const int l31 = lane & 31, lh = lane >> 5;
    const int srow = tid >> 3, sseg = tid & 7;
    const int qbase = qt2 * 128;
    const int qs = qbase + wave * 32;     // wave's 32-q slice
    const int q = qs + l31;               // this lane's q column

    // Q B-frags for all 4 ksteps, persistent across the kt loop.
    bf16x8 qf[4];
    {
        const bf16* qrow = Q + (size_t)q * DH_ + lh * 8;
        #pragma unroll
        for (int s = 0; s < 4; s++) qf[s] = *(const bf16x8*)(qrow + s * 16);
    }

    floatx16 accO[2];   // O^T: dh-tile dt -> rows dt*32+rho, col q
    #pragma unroll
    for (int dt = 0; dt < 2; dt++)
        #pragma unroll
        for (int e = 0; e < 16; e++) accO[dt][e] = 0.f;
    float lsum[4] = {0.f, 0.f, 0.f, 0.f};   // 4 independent add chains

    const bf16* kptr = K  + (size_t)(kt0 * 64 + srow) * DH_ + sseg * 8;
    const bf16* vptr = Vt + (size_t)srow * S_ + kt0 * 64 + sseg * 8;
    bf16x8 ka = *(const bf16x8*)kptr;
    bf16x8 kb = *(const bf16x8*)(kptr + 32 * DH_);
    bf16x8 va = *(const bf16x8*)vptr;
    bf16x8 vb = *(const bf16x8*)(vptr + (size_t)32 * S_);

    for (int kt = kt0; kt <= kt1; ++kt) {
        __syncthreads();
        *(bf16x8*)(Ks  + srow * 72 + sseg * 8) = ka;
        *(bf16x8*)(Ks  + (srow + 32) * 72 + sseg * 8) = kb;
        *(bf16x8*)(Vts + srow * 72 + sseg * 8) = va;
        *(bf16x8*)(Vts + (srow + 32) * 72 + sseg * 8) = vb;
        __syncthreads();
        if (kt < kt1) {
            kptr += 64 * DH_;
            vptr += 64;
            ka = *(const bf16x8*)kptr;
            kb = *(const bf16x8*)(kptr + 32 * DH_);
            va = *(const bf16x8*)vptr;
            vb = *(const bf16x8*)(vptr + (size_t)32 * S_);
        }

        const bool domask = (kt * 64 + 63 > qs);   // wave-uniform

        #pragma unroll
        for (int kk = 0; kk < 2; kk++) {
            // S^T = K Q^T for this 32-key tile
            floatx16 accS;
            #pragma unroll
            for (int e = 0; e < 16; e++) accS[e] = 0.f;
            #pragma unroll
            for (int s = 0; s < 4; s++) {
                bf16x8 kf = *(const bf16x8*)(Ks + (kk * 32 + l31) * 72 + s * 16 + lh * 8);
                accS = __builtin_amdgcn_mfma_f32_32x32x16_bf16(kf, qf[s], accS, 0, 0, 0);
            }

            // p = exp(s); pack to bf16 pairs; mask only on diagonal tiles
            unsigned pk1[4], pk2[4];
            if (domask) {
                const int keyb = kt * 64 + kk * 32 + 4 * lh;
                #pragma unroll
                for (int rq = 0; rq < 4; rq++) {
                    float p[4];
                    #pragma unroll
                    for (int rr = 0; rr < 4; rr++) {
                        float v = __expf(accS[4 * rq + rr]);
                        if (keyb + 8 * rq + rr > q) v = 0.f;
                        p[rr] = v;
                        lsum[rq] += v;
                    }
                    pk1[rq] = pack2(p[0], p[1]);
                    pk2[rq] = pack2(p[2], p[3]);
                }
            } else {
                #pragma unroll
                for (int rq = 0; rq < 4; rq++) {
                    float p[4];
                    #pragma unroll
                    for (int rr = 0; rr < 4; rr++) {
                        float v = __expf(accS[4 * rq + rr]);
                        p[rr] = v;
                        lsum[rq] += v;
                    }
                    pk1[rq] = pack2(p[0], p[1]);
                    pk2[rq] = pack2(p[2], p[3]);
                }
            }

            // PV for this kk's two ksteps: C->B-frag via shfl_xor(32)+selects
            #pragma unroll
            for (int sl = 0; sl < 2; sl++) {
                const int s = kk * 2 + sl;
                unsigned sendA = lh ? pk1[2 * sl] : pk1[2 * sl + 1];
                unsigned sendB = lh ? pk2[2 * sl] : pk2[2 * sl + 1];
                unsigned recvA = __shfl_xor(sendA, 32, 64);
                unsigned recvB = __shfl_xor(sendB, 32, 64);
                uint4 w;
                w.x = lh ? recvA : pk1[2 * sl];
                w.y = lh ? recvB : pk2[2 * sl];
                w.z = lh ? pk1[2 * sl + 1] : recvA;
                w.w = lh ? pk2[2 * sl + 1] : recvB;
                bf16x8 ptf = __builtin_bit_cast(bf16x8, w);
                #pragma unroll
                for (int dt = 0; dt < 2; dt++) {
                    bf16x8 vf = *(const bf16x8*)(Vts + (dt * 32 + l31) * 72 + s * 16 + lh * 8);
                    accO[dt] = __builtin_amdgcn_mfma_f32_32x32x16_bf16(vf, ptf, accO[dt], 0, 0, 0);
                }
            }
        }
    }

    // complete the row sum: own half + partner half
    const float Lr = (lsum[0] + lsum[1]) + (lsum[2] + lsum[3]);
    const float L = Lr + __shfl_xor(Lr, 32, 64);

    if (nch == 1) {
        const float inv = 1.0f / L;
        float* orow = out + (size_t)(b * S_ + q) * D_ + h * DH_;
        #pragma unroll
        for (int dt = 0; dt < 2; dt++)
            #pragma unroll
            for (int rq = 0; rq < 4; rq++) {
                float4 o;
                o.x = accO[dt][4 * rq + 0] * inv; o.y = accO[dt][4 * rq + 1] * inv;
                o.z = accO[dt][4 * rq + 2] * inv; o.w = accO[dt][4 * rq + 3] * inv;
                *(float4*)(orow + dt * 32 + 8 * rq + 4 * lh) = o;
            }
    } else {
        const int chunk = bh * 40 + chunk_off2(qt2) + c;
        bf16* obase = Opart + (size_t)chunk * 8192 + (wave * 32 + l31) * 64;
        #pragma unroll
        for (int dt = 0; dt < 2; dt++)
            #pragma unroll
            for (int rq = 0; rq < 4; rq++) {
                bf16x4 o;
                #pragma unroll
                for (int rr = 0; rr < 4; rr++) o[rr] = (bf16)accO[dt][4 * rq + rr];
                *(bf16x4*)(obase + dt * 32 + 8 * rq + 4 * lh) = o;
            }
        if (lh == 0) Lpart[chunk * 128 + wave * 32 + l31] = L;
    }
}

// ---------------- reduce: sum chunk partials, normalize, write out ----------
__global__ __launch_bounds__(256) void attn_reduce(const bf16* __restrict__ Opart,
                                                   const float* __restrict__ Lpart,
                                                   float* __restrict__ out)
{
    const int qt2 = 4 + blockIdx.x;   // 4..15
    const int bh = blockIdx.y;
    const int b = bh / H_, h = bh % H_;
    const int nch = (2 * qt2 + 9) >> 3;   // 2..4
    const int cb = bh * 40 + chunk_off2(qt2);

    const int e = threadIdx.x;
    const int ql = e >> 1, dh0 = (e & 1) * 32;

    float o[32];
    #pragma unroll
    for (int i = 0; i < 32; i++) o[i] = 0.f;
    float l = 0.f;

    for (int cidx = 0; cidx < nch; cidx++) {
        const bf16* p = Opart + (size_t)(cb + cidx) * 8192 + ql * 64 + dh0;
        #pragma unroll
        for (int m = 0; m < 4; m++) {
            bf16x8 v = *(const bf16x8*)(p + m * 8);
            #pragma unroll
            for (int k = 0; k < 8; k++) o[m * 8 + k] += (float)v[k];
        }
        l += Lpart[(cb + cidx) * 128 + ql];
    }
    float inv = 1.0f / l;
    float* orow = out + (size_t)(b * S_ + qt2 * 128 + ql) * D_ + h * DH_ + dh0;
    #pragma unroll
    for (int m = 0; m < 8; m++) {
        float4 v;
        v.x = o[m * 4 + 0] * inv; v.y = o[m * 4 + 1] * inv;
        v.z = o[m * 4 + 2] * inv; v.w = o[m * 4 + 3] * inv;
        *(float4*)(orow + m * 4) = v;
    }
}

extern "C" void kernel_launch(void* const* d_in, const int* in_sizes, int n_in,
                              void* d_out, int out_size, void* d_ws, size_t ws_size,
                              hipStream_t stream) {
    const float* hs = (const float*)d_in[0];
    // d_in[1] attention_mask: zeros, unused (matches reference)
    const float* Wq = (const float*)d_in[2];
    const float* bq = (const float*)d_in[3];
    const float* Wk = (const float*)d_in[4];
    const float* bk = (const float*)d_in[5];
    const float* Wv = (const float*)d_in[6];
    const float* bv = (const float*)d_in[7];
    float* out = (float*)d_out;

    bf16* Xb    = (bf16*)d_ws;                            // 8192*768
    bf16* Wt    = Xb + (size_t)8192 * 768;                // 3*768*768 (transposed)
    bf16* QKV   = Wt + (size_t)3 * 768 * 768;             // Q,K:[B,H,S,DH]; V:[B,H,DH,S]
    bf16* Opart = QKV + (size_t)3 * B_ * H_ * S_ * DH_;   // 1920*8192 bf16
    float* Lpart = (float*)(Opart + (size_t)1920 * 8192); // 1920*128 f32

    cvt_f32_bf16<<<6144, 256, 0, stream>>>(hs, Xb, 1572864);
    w_transpose<<<dim3(12, 12, 3), 256, 0, stream>>>(Wq, Wk, Wv, Wt);
    qkv_gemm<<<dim3(64, 6, 3), 256, 0, stream>>>(Xb, Wt, bq, bk, bv, QKV);
    attn_chunk<<<dim3(40, 48), 256, 0, stream>>>(QKV, out, Opart, Lpart);
    attn_reduce<<<dim3(12, 48), 256, 0, stream>>>(Opart, Lpart, out);
}